// Round 7
// baseline (417.395 us; speedup 1.0000x reference)
//
#include <hip/hip_runtime.h>

#define LLEN 16384
#define PAD 258  // 516B row stride = 129 dwords; 129%32==1 -> 2-way (free) LDS aliasing

typedef short bf16x8 __attribute__((ext_vector_type(8)));
typedef float f32x4 __attribute__((ext_vector_type(4)));

__device__ __forceinline__ unsigned bfbits(float f) {
  union { float f; unsigned u; } v; v.f = f;
  return (v.u + 0x7FFFu + ((v.u >> 16) & 1u)) >> 16;
}
__device__ __forceinline__ short f2bf(float f) { return (short)bfbits(f); }
__device__ __forceinline__ float bf2f(short s) {
  union { unsigned u; float f; } v;
  v.u = ((unsigned)(unsigned short)s) << 16;
  return v.f;
}
__device__ __forceinline__ float geluf(float x) {  // exact (gf path only)
  return 0.5f * x * (1.0f + erff(x * 0.70710678118654752f));
}
// Fast GELU for the conv chain (verified R4-R6: absmax unchanged at 4.77e-7)
__device__ __forceinline__ float gelu_fast(float x) {
  return x / (1.0f + __expf(-1.702f * x));
}
__device__ __forceinline__ float waveRedSum(float v) {
  #pragma unroll
  for (int o = 32; o > 0; o >>= 1) v += __shfl_xor(v, o, 64);
  return v;
}

// ---------------- K0: weights -> bf16, zero rowsum ----------------
__global__ __launch_bounds__(256) void k0_convert(
    const float* __restrict__ qw, const float* __restrict__ vw,
    const float* __restrict__ gw, const float* __restrict__ mw,
    short* __restrict__ qwb, short* __restrict__ vwb,
    short* __restrict__ gwb, short* __restrict__ mwb,
    float* __restrict__ rowsum) {
  int idx = blockIdx.x * 256 + threadIdx.x;  // 65536 threads
  qwb[idx] = f2bf(qw[idx]);
  vwb[idx] = f2bf(vw[idx]);
  mwb[idx] = f2bf(mw[idx]);
  if (idx < 4096) {
    int r = idx >> 8, c = idx & 255;
    gwb[idx] = (r < 4) ? f2bf(gw[r * 256 + c]) : (short)0;
  }
  if (idx < 2048) rowsum[idx] = 0.f;
}

// ---------------- K0t: transpose x [b][c][l] f32 -> xt tiles [l][c] bf16 ----
// Tile (b,lt) = 64 l x 256 c = exactly 32 KiB, stored in the mask-row upper
// half of row index (b*256+lt) (dead space until k4 writes m there).
__global__ __launch_bounds__(256) void k0t_transpose(
    const float* __restrict__ x, short* __restrict__ maskS) {
  int tile = blockIdx.x;  // b*256 + lt
  int b = tile >> 8, lt = tile & 255;
  int l0 = lt << 6;
  __shared__ short ts[64][PAD];
  int t = threadIdx.x;
  const float* xb = x + ((size_t)b << 22) + l0;
  int cg = t >> 4;        // c sub-row within iteration
  int le = (t & 15) * 4;  // l offset (16 lanes x float4 = 256B per c-row)
  #pragma unroll 4
  for (int k = 0; k < 16; ++k) {
    int c = k * 16 + cg;
    float4 v = *(const float4*)&xb[((size_t)c << 14) + le];
    ts[le + 0][c] = f2bf(v.x);
    ts[le + 1][c] = f2bf(v.y);
    ts[le + 2][c] = f2bf(v.z);
    ts[le + 3][c] = f2bf(v.w);
  }
  __syncthreads();
  short* out = maskS + ((size_t)tile << 15) + 16384;  // upper 32KiB of mask row
  #pragma unroll
  for (int i = 0; i < 8; ++i) {
    int p = i * 2048 + t * 8;
    *(bf16x8*)&out[p] = *(const bf16x8*)&ts[p >> 8][p & 255];
  }
}

// 64x64-per-wave GEMM over K=256 from LDS tile xs[l][c] (bf16, padded PAD).
// A = x fragment (M = l), B = weight fragment (N = e).
// acc[ef][lf][i] <-> e = ef*16 + (lane&15), l = lf*16 + 4*(lane>>4) + i
__device__ __forceinline__ void gemm64(const short* __restrict__ wmat,
                                       const short xs[64][PAD], int lane,
                                       f32x4 acc[4][4]) {
  int r = lane & 15, h = lane >> 4;
  #pragma unroll
  for (int k0 = 0; k0 < 256; k0 += 32) {
    bf16x8 xfr[4];
    #pragma unroll
    for (int lf = 0; lf < 4; ++lf)
      xfr[lf] = *(const bf16x8*)&xs[lf * 16 + r][k0 + 8 * h];
    #pragma unroll
    for (int ef = 0; ef < 4; ++ef) {
      bf16x8 wfr = *(const bf16x8*)(wmat + (ef * 16 + r) * 256 + k0 + 8 * h);
      #pragma unroll
      for (int lf = 0; lf < 4; ++lf)
        acc[ef][lf] = __builtin_amdgcn_mfma_f32_16x16x32_bf16(xfr[lf], wfr,
                                                              acc[ef][lf], 0, 0, 0);
    }
  }
}

// Packed epilogue: 4 consecutive-l f32 + bias -> 2 dwords of bf16 (8B store)
__device__ __forceinline__ void store_bf4(short* p, f32x4 a, float bias) {
  uint2 pk;
  pk.x = bfbits(a[0] + bias) | (bfbits(a[1] + bias) << 16);
  pk.y = bfbits(a[2] + bias) | (bfbits(a[3] + bias) << 16);
  *(uint2*)p = pk;
}

// ---------------- K1: focus0 = v_w@x+v_b (bf16), qz = q_w@x+q_b (bf16),
//                      gates = g_w@x+g_b.  Input from xt tiles (coalesced). ----
__global__ __launch_bounds__(256) void k1_qvg(
    const short* __restrict__ xtS, const short* __restrict__ vwb,
    const short* __restrict__ qwb, const short* __restrict__ gwb,
    const float* __restrict__ v_b, const float* __restrict__ q_b,
    const float* __restrict__ g_b, short* __restrict__ focus0,
    short* __restrict__ qzS, float* __restrict__ gates) {
  int b = blockIdx.x >> 8, lt = blockIdx.x & 255;
  int l0 = lt << 6;
  __shared__ short xs[64][PAD];
  int t = threadIdx.x;
  {
    const short* xt = xtS + ((size_t)blockIdx.x << 15) + 16384;
    #pragma unroll
    for (int i = 0; i < 8; ++i) {
      int p = i * 2048 + t * 8;
      *(bf16x8*)&xs[p >> 8][p & 255] = *(const bf16x8*)&xt[p];
    }
  }
  __syncthreads();
  int lane = t & 63, wave = t >> 6;
  int r = lane & 15, h = lane >> 4;
  int e0 = wave << 6;
  f32x4 acc[4][4];

  // ---- V GEMM -> focus0 (bf16)
  #pragma unroll
  for (int ef = 0; ef < 4; ++ef)
    #pragma unroll
    for (int lf = 0; lf < 4; ++lf)
      acc[ef][lf] = (f32x4){0.f, 0.f, 0.f, 0.f};
  gemm64(vwb + e0 * 256, xs, lane, acc);
  #pragma unroll
  for (int ef = 0; ef < 4; ++ef) {
    int e = e0 + ef * 16 + r;
    float bias = v_b[e];
    short* rowp = focus0 + ((size_t)((b << 8) | e) << 14) + l0 + 4 * h;
    #pragma unroll
    for (int lf = 0; lf < 4; ++lf)
      store_bf4(rowp + lf * 16, acc[ef][lf], bias);
  }

  // ---- Q GEMM -> qz (bf16, upper 32KiB of out-region rows; sigmoid in K5)
  #pragma unroll
  for (int ef = 0; ef < 4; ++ef)
    #pragma unroll
    for (int lf = 0; lf < 4; ++lf)
      acc[ef][lf] = (f32x4){0.f, 0.f, 0.f, 0.f};
  gemm64(qwb + e0 * 256, xs, lane, acc);
  #pragma unroll
  for (int ef = 0; ef < 4; ++ef) {
    int e = e0 + ef * 16 + r;
    float bias = q_b[e];
    short* rowp = qzS + (((size_t)((b << 8) | e) << 15) + 16384) + l0 + 4 * h;
    #pragma unroll
    for (int lf = 0; lf < 4; ++lf)
      store_bf4(rowp + lf * 16, acc[ef][lf], bias);
  }

  // ---- gates: 4x256 GEMM on wave 0 only (16-row padded weight tile)
  if (wave == 0) {
    f32x4 gacc[4];
    #pragma unroll
    for (int lf = 0; lf < 4; ++lf) gacc[lf] = (f32x4){0.f, 0.f, 0.f, 0.f};
    #pragma unroll
    for (int k0 = 0; k0 < 256; k0 += 32) {
      bf16x8 wfr = *(const bf16x8*)(gwb + r * 256 + k0 + 8 * h);
      #pragma unroll
      for (int lf = 0; lf < 4; ++lf) {
        bf16x8 xfr = *(const bf16x8*)&xs[lf * 16 + r][k0 + 8 * h];
        gacc[lf] = __builtin_amdgcn_mfma_f32_16x16x32_bf16(xfr, wfr, gacc[lf], 0, 0, 0);
      }
    }
    if (r < 4) {
      float gb = g_b[r];
      float* gp = gates + (((size_t)((b << 2) | r)) << 14) + l0 + 4 * h;
      #pragma unroll
      for (int lf = 0; lf < 4; ++lf) {
        float4 o = {gacc[lf][0] + gb, gacc[lf][1] + gb,
                    gacc[lf][2] + gb, gacc[lf][3] + gb};
        *(float4*)(gp + lf * 16) = o;
      }
    }
  }
}

// ---------------- K2: fused 3-level depthwise conv + gelu chain ----------------
__global__ __launch_bounds__(256) void k2_conv(
    const short* __restrict__ focus0, const float* __restrict__ gates,
    const float* __restrict__ f0_w, const float* __restrict__ f1_w,
    const float* __restrict__ f2_w, short* __restrict__ acc3S,
    float* __restrict__ rowsum) {
  int bx = blockIdx.x;
  int b = bx >> 12, c = (bx >> 4) & 255, lt = bx & 15;
  int l0 = lt << 10;
  __shared__ float s0[1036], s1[1034], s2[1030];
  __shared__ float rs[4];
  int t = threadIdx.x;
  const short* fp = focus0 + ((size_t)((b << 8) | c) << 14);
  if (lt > 0 && lt < 15) {
    const unsigned* fp2 = (const unsigned*)(fp + l0 - 6);
    for (int i2 = t; i2 < 518; i2 += 256) {
      unsigned u = fp2[i2];
      s0[2 * i2] = bf2f((short)(u & 0xFFFF));
      s0[2 * i2 + 1] = bf2f((short)(u >> 16));
    }
  } else {
    for (int i = t; i < 1036; i += 256) {
      int gl = l0 - 6 + i;
      s0[i] = (gl >= 0 && gl < LLEN) ? bf2f(fp[gl]) : 0.f;
    }
  }
  float w0[3], w1[5], w2[7];
  #pragma unroll
  for (int j = 0; j < 3; ++j) w0[j] = f0_w[c * 3 + j];
  #pragma unroll
  for (int j = 0; j < 5; ++j) w1[j] = f1_w[c * 5 + j];
  #pragma unroll
  for (int j = 0; j < 7; ++j) w2[j] = f2_w[c * 7 + j];
  __syncthreads();
  for (int i = t; i < 1034; i += 256) {
    int gl = l0 - 5 + i;
    float z = w0[0] * s0[i] + w0[1] * s0[i + 1] + w0[2] * s0[i + 2];
    s1[i] = (gl >= 0 && gl < LLEN) ? gelu_fast(z) : 0.f;
  }
  __syncthreads();
  for (int i = t; i < 1030; i += 256) {
    int gl = l0 - 3 + i;
    float z = w1[0] * s1[i] + w1[1] * s1[i + 1] + w1[2] * s1[i + 2] +
              w1[3] * s1[i + 3] + w1[4] * s1[i + 4];
    s2[i] = (gl >= 0 && gl < LLEN) ? gelu_fast(z) : 0.f;
  }
  __syncthreads();
  const float* gp = gates + ((size_t)(b << 2) << 14);
  short* op = acc3S + ((size_t)((b << 8) | c) << 15);  // lower 32KiB of mask row
  float lsum = 0.f;
  #pragma unroll
  for (int ii = 0; ii < 2; ++ii) {
    int i = 2 * t + 512 * ii;
    float z0 = w2[0] * s2[i] + w2[1] * s2[i + 1] + w2[2] * s2[i + 2] +
               w2[3] * s2[i + 3] + w2[4] * s2[i + 4] + w2[5] * s2[i + 5] +
               w2[6] * s2[i + 6];
    float z1 = w2[0] * s2[i + 1] + w2[1] * s2[i + 2] + w2[2] * s2[i + 3] +
               w2[3] * s2[i + 4] + w2[4] * s2[i + 5] + w2[5] * s2[i + 6] +
               w2[6] * s2[i + 7];
    float f30 = gelu_fast(z0), f31 = gelu_fast(z1);
    lsum += f30 + f31;
    int l = l0 + i;
    float a0 = s1[i + 5] * gp[l] + s2[i + 3] * gp[LLEN + l] + f30 * gp[2 * LLEN + l];
    float a1 = s1[i + 6] * gp[l + 1] + s2[i + 4] * gp[LLEN + l + 1] +
               f31 * gp[2 * LLEN + l + 1];
    *(unsigned*)&op[l] = bfbits(a0) | (bfbits(a1) << 16);
  }
  float wsv = waveRedSum(lsum);
  if ((t & 63) == 0) rs[t >> 6] = wsv;
  __syncthreads();
  if (t == 0) atomicAdd(&rowsum[(b << 8) | c], rs[0] + rs[1] + rs[2] + rs[3]);
}

// ---------------- K3b: wgf[b][o] = sum_c mix_w[o][c] * gelu(mean_f3[b][c]) ----
// Linearity: W@(acc3 + gf*g3) = W@acc3 + wgf*g3. Exact f32 path (no bf16).
__global__ __launch_bounds__(256) void k3b_wgf(
    const float* __restrict__ rowsum, const float* __restrict__ mix_w,
    float* __restrict__ wgf) {
  int b = blockIdx.x;  // 8 blocks
  int t = threadIdx.x;
  __shared__ float gf_s[256];
  gf_s[t] = geluf(rowsum[(b << 8) | t] * (1.0f / 16384.0f));
  __syncthreads();
  const float* wrow = mix_w + t * 256;  // o = t
  float s = 0.f;
  #pragma unroll 8
  for (int c = 0; c < 256; ++c) s += wrow[c] * gf_s[c];
  wgf[(b << 8) | t] = s;
}

// ---------------- K4: m = mix_w@acc3 + wgf*g3 + mix_b -> bf16 (upper half) ----
__global__ __launch_bounds__(256) void k4_mix(
    short* maskS, const float* __restrict__ gates, const float* __restrict__ wgf,
    const short* __restrict__ mwb, const float* __restrict__ mix_b) {
  int b = blockIdx.x >> 8, lt = blockIdx.x & 255;
  int l0 = lt << 6;
  __shared__ short xs[64][PAD];
  int t = threadIdx.x;
  {
    // Pure bf16 copy: thread t = channel c; 8 x b128 loads of acc3 row segment.
    int c = t;
    const unsigned short* arow =
        (const unsigned short*)maskS + (((size_t)((b << 8) | c)) << 15) + l0;
    #pragma unroll
    for (int i = 0; i < 8; ++i) {
      bf16x8 v = *(const bf16x8*)&arow[i * 8];
      #pragma unroll
      for (int j = 0; j < 8; ++j) xs[i * 8 + j][c] = v[j];
    }
  }
  __syncthreads();
  int lane = t & 63, wave = t >> 6;
  int r = lane & 15, h = lane >> 4;
  int e0 = wave << 6;
  f32x4 acc[4][4];
  #pragma unroll
  for (int ef = 0; ef < 4; ++ef)
    #pragma unroll
    for (int lf = 0; lf < 4; ++lf)
      acc[ef][lf] = (f32x4){0.f, 0.f, 0.f, 0.f};
  gemm64(mwb + e0 * 256, xs, lane, acc);
  float4 g3v[4];
  #pragma unroll
  for (int lf = 0; lf < 4; ++lf)
    g3v[lf] = *(const float4*)&gates[(((size_t)((b << 2) | 3)) << 14) + l0 +
                                     lf * 16 + 4 * h];
  #pragma unroll
  for (int ef = 0; ef < 4; ++ef) {
    int o = e0 + ef * 16 + r;
    float base = mix_b[o];
    float wg = wgf[(b << 8) | o];
    short* rowp = maskS + (((size_t)((b << 8) | o) << 15) + 16384) + l0 + 4 * h;
    #pragma unroll
    for (int lf = 0; lf < 4; ++lf) {
      uint2 pk;
      pk.x = bfbits(acc[ef][lf][0] + base + wg * g3v[lf].x) |
             (bfbits(acc[ef][lf][1] + base + wg * g3v[lf].y) << 16);
      pk.y = bfbits(acc[ef][lf][2] + base + wg * g3v[lf].z) |
             (bfbits(acc[ef][lf][3] + base + wg * g3v[lf].w) << 16);
      *(uint2*)(rowp + lf * 16) = pk;
    }
  }
}

// ---------------- K5: softmax over L from bf16 m; out = sigmoid(qz)*mask ----
__global__ __launch_bounds__(512) void k5_softmax(
    const short* __restrict__ maskS, const short* __restrict__ outS,
    float* __restrict__ maskF, float* __restrict__ outF) {
  int row = blockIdx.x;  // b*256 + o
  int t = threadIdx.x;   // 512 threads, 8 waves
  const short* mrow = maskS + ((size_t)row << 15) + 16384;
  const short* qrow = outS + ((size_t)row << 15) + 16384;
  float* mw = maskF + ((size_t)row << 14);
  float* ow = outF + ((size_t)row << 14);
  int lane = t & 63, wave = t >> 6;
  bf16x8 qv[4];
  float f[32];
  float lm = -3.0e38f;
  #pragma unroll
  for (int i = 0; i < 4; ++i) {
    bf16x8 mv = *(const bf16x8*)&mrow[i * 4096 + t * 8];
    qv[i] = *(const bf16x8*)&qrow[i * 4096 + t * 8];
    #pragma unroll
    for (int j = 0; j < 8; ++j) {
      float vf = bf2f(mv[j]);
      f[i * 8 + j] = vf;
      lm = fmaxf(lm, vf);
    }
  }
  __shared__ float redm[8], reds[8];
  {
    #pragma unroll
    for (int o = 32; o > 0; o >>= 1) lm = fmaxf(lm, __shfl_xor(lm, o, 64));
  }
  if (lane == 0) redm[wave] = lm;
  __syncthreads();
  float M = redm[0];
  #pragma unroll
  for (int w = 1; w < 8; ++w) M = fmaxf(M, redm[w]);
  float ls = 0.f;
  #pragma unroll
  for (int k = 0; k < 32; ++k) {
    f[k] = __expf(f[k] - M);
    ls += f[k];
  }
  float wsum = waveRedSum(ls);
  if (lane == 0) reds[wave] = wsum;
  __syncthreads();
  float S = reds[0];
  #pragma unroll
  for (int w = 1; w < 8; ++w) S += reds[w];
  float inv = 1.0f / S;
  #pragma unroll
  for (int i = 0; i < 4; ++i) {
    float mk[8], oo[8];
    #pragma unroll
    for (int j = 0; j < 8; ++j) {
      mk[j] = f[i * 8 + j] * inv;
      float sig = 1.0f / (1.0f + __expf(-bf2f(qv[i][j])));
      oo[j] = sig * mk[j];
    }
    float* mp = &mw[i * 4096 + t * 8];
    float* op = &ow[i * 4096 + t * 8];
    *(float4*)mp = (float4){mk[0], mk[1], mk[2], mk[3]};
    *(float4*)(mp + 4) = (float4){mk[4], mk[5], mk[6], mk[7]};
    *(float4*)op = (float4){oo[0], oo[1], oo[2], oo[3]};
    *(float4*)(op + 4) = (float4){oo[4], oo[5], oo[6], oo[7]};
  }
}

extern "C" void kernel_launch(void* const* d_in, const int* in_sizes, int n_in,
                              void* d_out, int out_size, void* d_ws, size_t ws_size,
                              hipStream_t stream) {
  const float* x     = (const float*)d_in[0];
  const float* q_w   = (const float*)d_in[1];
  const float* q_b   = (const float*)d_in[2];
  const float* v_w   = (const float*)d_in[3];
  const float* v_b   = (const float*)d_in[4];
  const float* g_w   = (const float*)d_in[5];
  const float* g_b   = (const float*)d_in[6];
  const float* f0_w  = (const float*)d_in[7];
  const float* f1_w  = (const float*)d_in[8];
  const float* f2_w  = (const float*)d_in[9];
  const float* mix_w = (const float*)d_in[10];
  const float* mix_b = (const float*)d_in[11];

  float* outbuf  = (float*)d_out;                       // out [8,256,16384] f32
  float* maskbuf = outbuf + (size_t)8 * 256 * 16384;    // mask [8,256,16384] f32
  short* outS  = (short*)outbuf;   // per-row: [32KiB out f32][32KiB qz bf16]
  short* maskS = (short*)maskbuf;  // per-row: [32KiB acc3][32KiB xt -> m]

  char* ws = (char*)d_ws;
  short* vwb    = (short*)(ws + 0);        // 131072 B
  short* qwb    = (short*)(ws + 131072);   // 131072 B
  short* mwb    = (short*)(ws + 262144);   // 131072 B
  short* gwb    = (short*)(ws + 393216);   // 8192 B
  float* rowsum = (float*)(ws + 401408);   // 8192 B
  float* wgf    = (float*)(ws + 409600);   // 8192 B
  float* gates  = (float*)(ws + 417792);   // 2097152 B
  short* focus0 = (short*)(ws + 2514944);  // 67108864 B

  k0_convert<<<dim3(256), dim3(256), 0, stream>>>(q_w, v_w, g_w, mix_w,
                                                  qwb, vwb, gwb, mwb, rowsum);
  k0t_transpose<<<dim3(2048), dim3(256), 0, stream>>>(x, maskS);
  k1_qvg<<<dim3(2048), dim3(256), 0, stream>>>(maskS, vwb, qwb, gwb, v_b, q_b,
                                               g_b, focus0, outS, gates);
  k2_conv<<<dim3(32768), dim3(256), 0, stream>>>(focus0, gates, f0_w, f1_w, f2_w,
                                                 maskS, rowsum);
  k3b_wgf<<<dim3(8), dim3(256), 0, stream>>>(rowsum, mix_w, wgf);
  k4_mix<<<dim3(2048), dim3(256), 0, stream>>>(maskS, gates, wgf, mwb, mix_b);
  k5_softmax<<<dim3(2048), dim3(512), 0, stream>>>(maskS, outS, maskbuf, outbuf);
}

// Round 8
// 388.888 us; speedup vs baseline: 1.0733x; 1.0733x over previous
//
#include <hip/hip_runtime.h>

#define LLEN 16384
#define PAD 258  // 516B row stride; 129 dwords == 1 mod 32 -> 2-way (free) LDS aliasing

typedef short bf16x8 __attribute__((ext_vector_type(8)));
typedef float f32x4 __attribute__((ext_vector_type(4)));

__device__ __forceinline__ unsigned bfbits(float f) {
  union { float f; unsigned u; } v; v.f = f;
  return (v.u + 0x7FFFu + ((v.u >> 16) & 1u)) >> 16;
}
__device__ __forceinline__ short f2bf(float f) { return (short)bfbits(f); }
__device__ __forceinline__ float bf2f(short s) {
  union { unsigned u; float f; } v;
  v.u = ((unsigned)(unsigned short)s) << 16;
  return v.f;
}
__device__ __forceinline__ float geluf(float x) {  // exact (gf path only)
  return 0.5f * x * (1.0f + erff(x * 0.70710678118654752f));
}
// Fast GELU for the conv chain (verified R4-R7: absmax unchanged at 4.77e-7)
__device__ __forceinline__ float gelu_fast(float x) {
  return x / (1.0f + __expf(-1.702f * x));
}

// ---------------- K0: weights -> bf16, zero rowsum ----------------
__global__ __launch_bounds__(256) void k0_convert(
    const float* __restrict__ qw, const float* __restrict__ vw,
    const float* __restrict__ gw, const float* __restrict__ mw,
    short* __restrict__ qwb, short* __restrict__ vwb,
    short* __restrict__ gwb, short* __restrict__ mwb,
    float* __restrict__ rowsum) {
  int idx = blockIdx.x * 256 + threadIdx.x;  // 65536 threads
  qwb[idx] = f2bf(qw[idx]);
  vwb[idx] = f2bf(vw[idx]);
  mwb[idx] = f2bf(mw[idx]);
  if (idx < 4096) {
    int r = idx >> 8, c = idx & 255;
    gwb[idx] = (r < 4) ? f2bf(gw[r * 256 + c]) : (short)0;
  }
  if (idx < 2048) rowsum[idx] = 0.f;
}

// 64x64-per-wave GEMM over K=256 from LDS tile xs[l][c] (bf16, stride PAD).
// A = x fragment (M = l), B = weight fragment (N = e).
// acc[ef][lf][i] <-> e = ef*16 + (lane&15), l = lf*16 + 4*(lane>>4) + i
__device__ __forceinline__ void gemm64(const short* __restrict__ wmat,
                                       const short (*xs)[PAD], int lane,
                                       f32x4 acc[4][4]) {
  int r = lane & 15, h = lane >> 4;
  #pragma unroll
  for (int k0 = 0; k0 < 256; k0 += 32) {
    bf16x8 xfr[4];
    #pragma unroll
    for (int lf = 0; lf < 4; ++lf)
      xfr[lf] = *(const bf16x8*)&xs[lf * 16 + r][k0 + 8 * h];
    #pragma unroll
    for (int ef = 0; ef < 4; ++ef) {
      bf16x8 wfr = *(const bf16x8*)(wmat + (ef * 16 + r) * 256 + k0 + 8 * h);
      #pragma unroll
      for (int lf = 0; lf < 4; ++lf)
        acc[ef][lf] = __builtin_amdgcn_mfma_f32_16x16x32_bf16(xfr[lf], wfr,
                                                              acc[ef][lf], 0, 0, 0);
    }
  }
}

// Packed epilogue: 4 consecutive-l f32 + bias -> 2 dwords of bf16 (8B store)
__device__ __forceinline__ void store_bf4(short* p, f32x4 a, float bias) {
  uint2 pk;
  pk.x = bfbits(a[0] + bias) | (bfbits(a[1] + bias) << 16);
  pk.y = bfbits(a[2] + bias) | (bfbits(a[3] + bias) << 16);
  *(uint2*)p = pk;
}

// ---------------- KF: fused V/Q/G GEMMs + conv chain + mix GEMM ----------------
// Per (b, lt): stage x[76 l][256 c] bf16 (halo 6), compute:
//   focus0 = V GEMM over 76 l -> fs (LDS); qz = Q GEMM central 64 -> HBM bf16;
//   gates  = G GEMM central 64 -> g0..g2 in fs spare cols, g3 -> HBM f32;
//   conv chain streamed per-channel (lane = channel) -> acc3 -> xs region (LDS);
//   m_partial = mix GEMM(acc3) + mix_b -> HBM bf16;  rowsum(f3) atomics.
// Global-focus term deferred to K5 via linearity: m = m_partial + wgf*g3.
__global__ __launch_bounds__(256) void kf_fused(
    const float* __restrict__ x, const short* __restrict__ vwb,
    const short* __restrict__ qwb, const short* __restrict__ gwb,
    const short* __restrict__ mwb, const float* __restrict__ v_b,
    const float* __restrict__ q_b, const float* __restrict__ g_b,
    const float* __restrict__ mix_b, const float* __restrict__ f0_w,
    const float* __restrict__ f1_w, const float* __restrict__ f2_w,
    short* __restrict__ qzS, short* __restrict__ mS,
    float* __restrict__ gates3, float* __restrict__ rowsum) {
  int b = blockIdx.x >> 8, lt = blockIdx.x & 255;
  int l0 = lt << 6;
  __shared__ short xs[76][PAD];  // x tile [idx][c]; later reused as acc3 [ci][c]
  __shared__ short fs[256][82];  // focus0 rows [c][idx 0..75]; cols 76..81 = g0..g2 f32
  int t = threadIdx.x;

  // ---- Phase 0: stage x (thread t = channel c; column scatter, 2-way free)
  {
    int c = t;
    if (lt != 0 && lt != 255) {
      const float* xb = x + ((size_t)b << 22) + ((size_t)c << 14) + (l0 - 6);
      #pragma unroll 4
      for (int k = 0; k < 38; ++k) {
        float2 v = *(const float2*)&xb[2 * k];
        xs[2 * k][c] = f2bf(v.x);
        xs[2 * k + 1][c] = f2bf(v.y);
      }
    } else {
      const float* xr = x + ((size_t)b << 22) + ((size_t)c << 14);
      for (int j = 0; j < 76; ++j) {
        int pos = l0 - 6 + j;
        xs[j][c] = ((unsigned)pos < (unsigned)LLEN) ? f2bf(xr[pos]) : (short)0;
      }
    }
  }
  __syncthreads();

  int lane = t & 63, wave = t >> 6;
  int r = lane & 15, h = lane >> 4;
  int e0 = wave << 6;

  // ---- Phase 1a: V GEMM over 76(80) l -> focus0 in fs
  {
    f32x4 vacc[4][5];
    #pragma unroll
    for (int ef = 0; ef < 4; ++ef)
      #pragma unroll
      for (int lf = 0; lf < 5; ++lf)
        vacc[ef][lf] = (f32x4){0.f, 0.f, 0.f, 0.f};
    #pragma unroll
    for (int k0 = 0; k0 < 256; k0 += 32) {
      bf16x8 xfr[5];
      #pragma unroll
      for (int lf = 0; lf < 5; ++lf)  // lf=4 rows 76..79 read past xs (into fs,
        xfr[lf] = *(const bf16x8*)&xs[lf * 16 + r][k0 + 8 * h];  // garbage ok: outputs skipped)
      #pragma unroll
      for (int ef = 0; ef < 4; ++ef) {
        bf16x8 wfr = *(const bf16x8*)(vwb + (e0 + ef * 16 + r) * 256 + k0 + 8 * h);
        #pragma unroll
        for (int lf = 0; lf < 5; ++lf)
          vacc[ef][lf] = __builtin_amdgcn_mfma_f32_16x16x32_bf16(xfr[lf], wfr,
                                                                 vacc[ef][lf], 0, 0, 0);
      }
    }
    #pragma unroll
    for (int ef = 0; ef < 4; ++ef) {
      int e = e0 + ef * 16 + r;
      float bias = v_b[e];
      #pragma unroll
      for (int lf = 0; lf < 5; ++lf) {
        if (lf < 4 || h < 3) {  // skip idx 76..79 (don't clobber g-columns)
          int idx0 = lf * 16 + 4 * h;
          *(unsigned*)&fs[e][idx0] =
              bfbits(vacc[ef][lf][0] + bias) | (bfbits(vacc[ef][lf][1] + bias) << 16);
          *(unsigned*)&fs[e][idx0 + 2] =
              bfbits(vacc[ef][lf][2] + bias) | (bfbits(vacc[ef][lf][3] + bias) << 16);
        }
      }
    }
  }

  // ---- Phase 1b: Q GEMM central 64 l (xs rows 6..69) -> qz bf16
  {
    f32x4 qacc[4][4];
    #pragma unroll
    for (int ef = 0; ef < 4; ++ef)
      #pragma unroll
      for (int lf = 0; lf < 4; ++lf)
        qacc[ef][lf] = (f32x4){0.f, 0.f, 0.f, 0.f};
    gemm64(qwb + e0 * 256, (const short(*)[PAD])&xs[6], lane, qacc);
    #pragma unroll
    for (int ef = 0; ef < 4; ++ef) {
      int e = e0 + ef * 16 + r;
      float bias = q_b[e];
      short* rowp = qzS + (((size_t)((b << 8) | e) << 15) + 16384) + l0 + 4 * h;
      #pragma unroll
      for (int lf = 0; lf < 4; ++lf)
        store_bf4(rowp + lf * 16, qacc[ef][lf], bias);
    }
  }

  // ---- Phase 1c: G GEMM central 64 l (wave 0): g0..g2 -> fs cols 76..81, g3 -> HBM
  if (wave == 0) {
    f32x4 gacc[4];
    #pragma unroll
    for (int lf = 0; lf < 4; ++lf) gacc[lf] = (f32x4){0.f, 0.f, 0.f, 0.f};
    #pragma unroll
    for (int k0 = 0; k0 < 256; k0 += 32) {
      bf16x8 wfr = *(const bf16x8*)(gwb + r * 256 + k0 + 8 * h);
      #pragma unroll
      for (int lf = 0; lf < 4; ++lf) {
        bf16x8 xfr = *(const bf16x8*)&xs[6 + lf * 16 + r][k0 + 8 * h];
        gacc[lf] = __builtin_amdgcn_mfma_f32_16x16x32_bf16(xfr, wfr, gacc[lf], 0, 0, 0);
      }
    }
    if (r < 3) {  // g0..g2 -> fs[ci] bytes 152+4r (cols 76..81)
      float gb = g_b[r];
      #pragma unroll
      for (int lf = 0; lf < 4; ++lf)
        #pragma unroll
        for (int i = 0; i < 4; ++i) {
          int ci = lf * 16 + 4 * h + i;
          *(float*)((char*)&fs[ci][0] + 152 + 4 * r) = gacc[lf][i] + gb;
        }
    } else if (r == 3) {  // g3 -> HBM f32 (needed by K5)
      float gb = g_b[3];
      float* gp = gates3 + ((size_t)b << 14) + l0 + 4 * h;
      #pragma unroll
      for (int lf = 0; lf < 4; ++lf) {
        float4 o = {gacc[lf][0] + gb, gacc[lf][1] + gb,
                    gacc[lf][2] + gb, gacc[lf][3] + gb};
        *(float4*)(gp + lf * 16) = o;
      }
    }
  }
  __syncthreads();

  // ---- Phase 2: streaming conv chain (lane = channel), acc3 -> xs[ci][c]
  {
    int c = t;
    float w0_[3], w1_[5], w2_[7];
    #pragma unroll
    for (int j = 0; j < 3; ++j) w0_[j] = f0_w[c * 3 + j];
    #pragma unroll
    for (int j = 0; j < 5; ++j) w1_[j] = f1_w[c * 5 + j];
    #pragma unroll
    for (int j = 0; j < 7; ++j) w2_[j] = f2_w[c * 7 + j];
    float s0a = 0.f, s0b = 0.f, s0c = 0.f;
    float s1h[6], s2h[7];
    #pragma unroll
    for (int j = 0; j < 6; ++j) s1h[j] = 0.f;
    #pragma unroll
    for (int j = 0; j < 7; ++j) s2h[j] = 0.f;
    float lsum = 0.f;
    #pragma unroll 4
    for (int idx = 0; idx < 76; ++idx) {
      int pos = l0 - 6 + idx;
      float s0v = ((unsigned)pos < (unsigned)LLEN) ? bf2f(fs[c][idx]) : 0.f;
      s0a = s0b; s0b = s0c; s0c = s0v;
      // s1 center pos-1: w0 . s0[pos-2..pos]
      float z1 = w0_[0] * s0a + w0_[1] * s0b + w0_[2] * s0c;
      float s1v = ((unsigned)(pos - 1) < (unsigned)LLEN) ? gelu_fast(z1) : 0.f;
      s1h[0] = s1h[1]; s1h[1] = s1h[2]; s1h[2] = s1h[3];
      s1h[3] = s1h[4]; s1h[4] = s1h[5]; s1h[5] = s1v;
      // s2 center pos-3: w1 . s1[pos-5..pos-1] = s1h[1..5]
      float z2 = w1_[0] * s1h[1] + w1_[1] * s1h[2] + w1_[2] * s1h[3] +
                 w1_[3] * s1h[4] + w1_[4] * s1h[5];
      float s2v = ((unsigned)(pos - 3) < (unsigned)LLEN) ? gelu_fast(z2) : 0.f;
      s2h[0] = s2h[1]; s2h[1] = s2h[2]; s2h[2] = s2h[3]; s2h[3] = s2h[4];
      s2h[4] = s2h[5]; s2h[5] = s2h[6]; s2h[6] = s2v;
      // f3 center pos-6: w2 . s2[pos-9..pos-3] = s2h[0..6]
      float z3 = w2_[0] * s2h[0] + w2_[1] * s2h[1] + w2_[2] * s2h[2] +
                 w2_[3] * s2h[3] + w2_[4] * s2h[4] + w2_[5] * s2h[5] +
                 w2_[6] * s2h[6];
      float f3v = ((unsigned)(pos - 6) < (unsigned)LLEN) ? gelu_fast(z3) : 0.f;
      int ci = idx - 12;  // center pos-6 = l0 + ci
      if ((unsigned)ci < 64u) {
        lsum += f3v;
        const char* grow = (const char*)&fs[ci][0];
        float g0 = *(const float*)(grow + 152);
        float g1 = *(const float*)(grow + 156);
        float g2 = *(const float*)(grow + 160);
        // s1 @ pos-6 = s1h[0]; s2 @ pos-6 = s2h[3]
        float accv = s1h[0] * g0 + s2h[3] * g1 + f3v * g2;
        xs[ci][c] = f2bf(accv);
      }
    }
    atomicAdd(&rowsum[(b << 8) | c], lsum);
  }
  __syncthreads();

  // ---- Phase 3: mix GEMM on acc3 (xs rows 0..63) -> m_partial bf16
  {
    f32x4 macc[4][4];
    #pragma unroll
    for (int ef = 0; ef < 4; ++ef)
      #pragma unroll
      for (int lf = 0; lf < 4; ++lf)
        macc[ef][lf] = (f32x4){0.f, 0.f, 0.f, 0.f};
    gemm64(mwb + e0 * 256, (const short(*)[PAD])&xs[0], lane, macc);
    #pragma unroll
    for (int ef = 0; ef < 4; ++ef) {
      int o = e0 + ef * 16 + r;
      float base = mix_b[o];
      short* rowp = mS + (((size_t)((b << 8) | o) << 15) + 16384) + l0 + 4 * h;
      #pragma unroll
      for (int lf = 0; lf < 4; ++lf)
        store_bf4(rowp + lf * 16, macc[ef][lf], base);
    }
  }
}

// ---------------- K3b: wgf[b][o] = sum_c mix_w[o][c] * gelu(mean_f3[b][c]) ----
__global__ __launch_bounds__(256) void k3b_wgf(
    const float* __restrict__ rowsum, const float* __restrict__ mix_w,
    float* __restrict__ wgf) {
  int b = blockIdx.x;  // 8 blocks
  int t = threadIdx.x;
  __shared__ float gf_s[256];
  gf_s[t] = geluf(rowsum[(b << 8) | t] * (1.0f / 16384.0f));
  __syncthreads();
  const float* wrow = mix_w + t * 256;  // o = t
  float s = 0.f;
  #pragma unroll 8
  for (int c = 0; c < 256; ++c) s += wrow[c] * gf_s[c];
  wgf[(b << 8) | t] = s;
}

// ---------------- K5: m = m_partial + wgf*g3; softmax over L;
//                      mask -> f32, out = sigmoid(qz)*mask ----------------
__global__ __launch_bounds__(512) void k5_softmax(
    const short* __restrict__ maskS, const short* __restrict__ outS,
    const float* __restrict__ gates3, const float* __restrict__ wgf,
    float* __restrict__ maskF, float* __restrict__ outF) {
  int row = blockIdx.x;  // b*256 + o
  int b = row >> 8;
  int t = threadIdx.x;   // 512 threads, 8 waves
  const short* mrow = maskS + ((size_t)row << 15) + 16384;
  const short* qrow = outS + ((size_t)row << 15) + 16384;
  const float* g3r = gates3 + ((size_t)b << 14);
  float wg = wgf[row];
  float* mw = maskF + ((size_t)row << 14);
  float* ow = outF + ((size_t)row << 14);
  int lane = t & 63, wave = t >> 6;
  bf16x8 qv[4];
  float f[32];
  float lm = -3.0e38f;
  #pragma unroll
  for (int i = 0; i < 4; ++i) {
    bf16x8 mv = *(const bf16x8*)&mrow[i * 4096 + t * 8];
    qv[i] = *(const bf16x8*)&qrow[i * 4096 + t * 8];
    float4 ga = *(const float4*)&g3r[i * 4096 + t * 8];
    float4 gb = *(const float4*)&g3r[i * 4096 + t * 8 + 4];
    float gj[8] = {ga.x, ga.y, ga.z, ga.w, gb.x, gb.y, gb.z, gb.w};
    #pragma unroll
    for (int j = 0; j < 8; ++j) {
      float vf = bf2f(mv[j]) + wg * gj[j];
      f[i * 8 + j] = vf;
      lm = fmaxf(lm, vf);
    }
  }
  __shared__ float redm[8], reds[8];
  {
    #pragma unroll
    for (int o = 32; o > 0; o >>= 1) lm = fmaxf(lm, __shfl_xor(lm, o, 64));
  }
  if (lane == 0) redm[wave] = lm;
  __syncthreads();  // also drains all global loads before writes below
  float M = redm[0];
  #pragma unroll
  for (int w = 1; w < 8; ++w) M = fmaxf(M, redm[w]);
  float ls = 0.f;
  #pragma unroll
  for (int k = 0; k < 32; ++k) {
    f[k] = __expf(f[k] - M);
    ls += f[k];
  }
  {
    #pragma unroll
    for (int o = 32; o > 0; o >>= 1) ls += __shfl_xor(ls, o, 64);
  }
  if (lane == 0) reds[wave] = ls;
  __syncthreads();
  float S = reds[0];
  #pragma unroll
  for (int w = 1; w < 8; ++w) S += reds[w];
  float inv = 1.0f / S;
  #pragma unroll
  for (int i = 0; i < 4; ++i) {
    float mk[8], oo[8];
    #pragma unroll
    for (int j = 0; j < 8; ++j) {
      mk[j] = f[i * 8 + j] * inv;
      float sig = 1.0f / (1.0f + __expf(-bf2f(qv[i][j])));
      oo[j] = sig * mk[j];
    }
    float* mp = &mw[i * 4096 + t * 8];
    float* op = &ow[i * 4096 + t * 8];
    *(float4*)mp = (float4){mk[0], mk[1], mk[2], mk[3]};
    *(float4*)(mp + 4) = (float4){mk[4], mk[5], mk[6], mk[7]};
    *(float4*)op = (float4){oo[0], oo[1], oo[2], oo[3]};
    *(float4*)(op + 4) = (float4){oo[4], oo[5], oo[6], oo[7]};
  }
}

extern "C" void kernel_launch(void* const* d_in, const int* in_sizes, int n_in,
                              void* d_out, int out_size, void* d_ws, size_t ws_size,
                              hipStream_t stream) {
  const float* x     = (const float*)d_in[0];
  const float* q_w   = (const float*)d_in[1];
  const float* q_b   = (const float*)d_in[2];
  const float* v_w   = (const float*)d_in[3];
  const float* v_b   = (const float*)d_in[4];
  const float* g_w   = (const float*)d_in[5];
  const float* g_b   = (const float*)d_in[6];
  const float* f0_w  = (const float*)d_in[7];
  const float* f1_w  = (const float*)d_in[8];
  const float* f2_w  = (const float*)d_in[9];
  const float* mix_w = (const float*)d_in[10];
  const float* mix_b = (const float*)d_in[11];

  float* outbuf  = (float*)d_out;                       // out [8,256,16384] f32
  float* maskbuf = outbuf + (size_t)8 * 256 * 16384;    // mask [8,256,16384] f32
  short* outS  = (short*)outbuf;   // per-row: [32KiB out f32][32KiB qz bf16]
  short* maskS = (short*)maskbuf;  // per-row: [32KiB unused][32KiB m_partial bf16]

  char* ws = (char*)d_ws;
  short* vwb    = (short*)(ws + 0);        // 131072 B
  short* qwb    = (short*)(ws + 131072);   // 131072 B
  short* mwb    = (short*)(ws + 262144);   // 131072 B
  short* gwb    = (short*)(ws + 393216);   // 8192 B (16x256 bf16, rows>=4 zero)
  float* rowsum = (float*)(ws + 401408);   // 8192 B
  float* wgf    = (float*)(ws + 409600);   // 8192 B
  float* gates3 = (float*)(ws + 417792);   // 8*16384*4 = 524288 B

  k0_convert<<<dim3(256), dim3(256), 0, stream>>>(q_w, v_w, g_w, mix_w,
                                                  qwb, vwb, gwb, mwb, rowsum);
  kf_fused<<<dim3(2048), dim3(256), 0, stream>>>(x, vwb, qwb, gwb, mwb,
                                                 v_b, q_b, g_b, mix_b,
                                                 f0_w, f1_w, f2_w,
                                                 outS, maskS, gates3, rowsum);
  k3b_wgf<<<dim3(8), dim3(256), 0, stream>>>(rowsum, mix_w, wgf);
  k5_softmax<<<dim3(2048), dim3(512), 0, stream>>>(maskS, outS, gates3, wgf,
                                                   maskbuf, outbuf);
}

// Round 9
// 377.934 us; speedup vs baseline: 1.1044x; 1.0290x over previous
//
#include <hip/hip_runtime.h>

#define LLEN 16384
#define PAD 258  // 516B row stride; 129 dwords == 1 mod 32 -> 2-way (free) LDS aliasing

typedef short bf16x8 __attribute__((ext_vector_type(8)));
typedef float f32x4 __attribute__((ext_vector_type(4)));

__device__ __forceinline__ unsigned bfbits(float f) {
  union { float f; unsigned u; } v; v.f = f;
  return (v.u + 0x7FFFu + ((v.u >> 16) & 1u)) >> 16;
}
__device__ __forceinline__ short f2bf(float f) { return (short)bfbits(f); }
__device__ __forceinline__ float bf2f(short s) {
  union { unsigned u; float f; } v;
  v.u = ((unsigned)(unsigned short)s) << 16;
  return v.f;
}
// v_rcp_f32: 1 op vs ~10 for IEEE divide; rel err ~1.2e-7 (safe: outputs ~6e-5,
// induced error ~1e-11 << 4.8e-7 current absmax)
__device__ __forceinline__ float fastrcp(float x) {
  float r;
  asm("v_rcp_f32 %0, %1" : "=v"(r) : "v"(x));
  return r;
}
__device__ __forceinline__ float geluf(float x) {  // exact (gf path only)
  return 0.5f * x * (1.0f + erff(x * 0.70710678118654752f));
}
// Fast GELU for conv chain (verified R4-R8: absmax unchanged at 4.77e-7)
__device__ __forceinline__ float gelu_fast(float x) {
  return x * fastrcp(1.0f + __expf(-1.702f * x));
}
__device__ __forceinline__ float waveRedSum(float v) {
  #pragma unroll
  for (int o = 32; o > 0; o >>= 1) v += __shfl_xor(v, o, 64);
  return v;
}

// ---------------- K0: weights -> bf16, zero rowsum ----------------
__global__ __launch_bounds__(256) void k0_convert(
    const float* __restrict__ qw, const float* __restrict__ vw,
    const float* __restrict__ gw, const float* __restrict__ mw,
    short* __restrict__ qwb, short* __restrict__ vwb,
    short* __restrict__ gwb, short* __restrict__ mwb,
    float* __restrict__ rowsum) {
  int idx = blockIdx.x * 256 + threadIdx.x;  // 65536 threads
  qwb[idx] = f2bf(qw[idx]);
  vwb[idx] = f2bf(vw[idx]);
  mwb[idx] = f2bf(mw[idx]);
  if (idx < 4096) {
    int r = idx >> 8, c = idx & 255;
    gwb[idx] = (r < 4) ? f2bf(gw[r * 256 + c]) : (short)0;
  }
  if (idx < 2048) rowsum[idx] = 0.f;
}

// 64x64-per-wave GEMM over K=256 from LDS tile xs[l][c] (bf16, stride PAD).
// A = x fragment (M = l), B = weight fragment (N = e).
// acc[ef][lf][i] <-> e = ef*16 + (lane&15), l = lf*16 + 4*(lane>>4) + i
// (PROVEN R3 shape -- unchanged.)
__device__ __forceinline__ void gemm64(const short* __restrict__ wmat,
                                       const short (*xs)[PAD], int lane,
                                       f32x4 acc[4][4]) {
  int r = lane & 15, h = lane >> 4;
  #pragma unroll
  for (int k0 = 0; k0 < 256; k0 += 32) {
    bf16x8 xfr[4];
    #pragma unroll
    for (int lf = 0; lf < 4; ++lf)
      xfr[lf] = *(const bf16x8*)&xs[lf * 16 + r][k0 + 8 * h];
    #pragma unroll
    for (int ef = 0; ef < 4; ++ef) {
      bf16x8 wfr = *(const bf16x8*)(wmat + (ef * 16 + r) * 256 + k0 + 8 * h);
      #pragma unroll
      for (int lf = 0; lf < 4; ++lf)
        acc[ef][lf] = __builtin_amdgcn_mfma_f32_16x16x32_bf16(xfr[lf], wfr,
                                                              acc[ef][lf], 0, 0, 0);
    }
  }
}

// Packed epilogue: 4 consecutive-l f32 + bias -> 2 dwords of bf16 (8B store)
__device__ __forceinline__ void store_bf4(short* p, f32x4 a, float bias) {
  uint2 pk;
  pk.x = bfbits(a[0] + bias) | (bfbits(a[1] + bias) << 16);
  pk.y = bfbits(a[2] + bias) | (bfbits(a[3] + bias) << 16);
  *(uint2*)p = pk;
}

// ---------------- K1: focus0 = v_w@x+v_b (bf16), qz = q_w@x+q_b (bf16),
//     gates = g_w@x+g_b.  128-l tile, 512 thr = 8 waves of PROVEN 64e x 64l. ----
__global__ __launch_bounds__(512) void k1_qvg(
    const float* __restrict__ x, const short* __restrict__ vwb,
    const short* __restrict__ qwb, const short* __restrict__ gwb,
    const float* __restrict__ v_b, const float* __restrict__ q_b,
    const float* __restrict__ g_b, short* __restrict__ focus0,
    short* __restrict__ qzS, float* __restrict__ gates) {
  int b = blockIdx.x >> 7, lt = blockIdx.x & 127;
  int l0 = lt << 7;  // 128 l per tile
  __shared__ short xs[128][PAD];
  int t = threadIdx.x;
  {
    // float4 staging: 32 lanes x 16B = 512B contiguous per channel row.
    int lq = (t & 31) * 4, cg = t >> 5;  // 16 c-groups
    const float* xb = x + ((size_t)b << 22) + l0 + lq;
    #pragma unroll
    for (int rep = 0; rep < 8; ++rep) {
      int c = rep * 32 + cg * 2;
      float4 va = *(const float4*)&xb[(size_t)c << 14];
      float4 vb = *(const float4*)&xb[((size_t)c + 1) << 14];
      *(unsigned*)&xs[lq + 0][c] = bfbits(va.x) | (bfbits(vb.x) << 16);
      *(unsigned*)&xs[lq + 1][c] = bfbits(va.y) | (bfbits(vb.y) << 16);
      *(unsigned*)&xs[lq + 2][c] = bfbits(va.z) | (bfbits(vb.z) << 16);
      *(unsigned*)&xs[lq + 3][c] = bfbits(va.w) | (bfbits(vb.w) << 16);
    }
  }
  __syncthreads();
  int lane = t & 63, wave = t >> 6;
  int we = wave & 3, wl = wave >> 2;  // 4 e-ranges x 2 l-subtiles
  int r = lane & 15, h = lane >> 4;
  int e0 = we << 6;
  const short (*xsl)[PAD] = (const short (*)[PAD])&xs[wl << 6];
  int lbase = l0 + (wl << 6) + 4 * h;
  f32x4 acc[4][4];

  // ---- V GEMM -> focus0 (bf16)
  #pragma unroll
  for (int ef = 0; ef < 4; ++ef)
    #pragma unroll
    for (int lf = 0; lf < 4; ++lf)
      acc[ef][lf] = (f32x4){0.f, 0.f, 0.f, 0.f};
  gemm64(vwb + e0 * 256, xsl, lane, acc);
  #pragma unroll
  for (int ef = 0; ef < 4; ++ef) {
    int e = e0 + ef * 16 + r;
    float bias = v_b[e];
    short* rowp = focus0 + ((size_t)((b << 8) | e) << 14) + lbase;
    #pragma unroll
    for (int lf = 0; lf < 4; ++lf)
      store_bf4(rowp + lf * 16, acc[ef][lf], bias);
  }

  // ---- Q GEMM -> qz (bf16, upper 32KiB of out-region rows; sigmoid in K5)
  #pragma unroll
  for (int ef = 0; ef < 4; ++ef)
    #pragma unroll
    for (int lf = 0; lf < 4; ++lf)
      acc[ef][lf] = (f32x4){0.f, 0.f, 0.f, 0.f};
  gemm64(qwb + e0 * 256, xsl, lane, acc);
  #pragma unroll
  for (int ef = 0; ef < 4; ++ef) {
    int e = e0 + ef * 16 + r;
    float bias = q_b[e];
    short* rowp = qzS + (((size_t)((b << 8) | e) << 15) + 16384) + lbase;
    #pragma unroll
    for (int lf = 0; lf < 4; ++lf)
      store_bf4(rowp + lf * 16, acc[ef][lf], bias);
  }

  // ---- gates: waves with we==0 (wl = 0,1 cover the two 64-l subtiles)
  if (we == 0) {
    f32x4 gacc[4];
    #pragma unroll
    for (int lf = 0; lf < 4; ++lf) gacc[lf] = (f32x4){0.f, 0.f, 0.f, 0.f};
    #pragma unroll
    for (int k0 = 0; k0 < 256; k0 += 32) {
      bf16x8 wfr = *(const bf16x8*)(gwb + r * 256 + k0 + 8 * h);
      #pragma unroll
      for (int lf = 0; lf < 4; ++lf) {
        bf16x8 xfr = *(const bf16x8*)&xsl[lf * 16 + r][k0 + 8 * h];
        gacc[lf] = __builtin_amdgcn_mfma_f32_16x16x32_bf16(xfr, wfr, gacc[lf], 0, 0, 0);
      }
    }
    if (r < 4) {  // col = gate row g = r
      float gb = g_b[r];
      float* gp = gates + (((size_t)((b << 2) | r)) << 14) + lbase;
      #pragma unroll
      for (int lf = 0; lf < 4; ++lf) {
        float4 o = {gacc[lf][0] + gb, gacc[lf][1] + gb,
                    gacc[lf][2] + gb, gacc[lf][3] + gb};
        *(float4*)(gp + lf * 16) = o;
      }
    }
  }
}

// ---------------- K2: fused 3-level depthwise conv + gelu chain,
//                      acc3 (bf16) -> lower half of mask rows; rowsum atomics ----
__global__ __launch_bounds__(256) void k2_conv(
    const short* __restrict__ focus0, const float* __restrict__ gates,
    const float* __restrict__ f0_w, const float* __restrict__ f1_w,
    const float* __restrict__ f2_w, short* __restrict__ acc3S,
    float* __restrict__ rowsum) {
  int bx = blockIdx.x;
  int b = bx >> 12, c = (bx >> 4) & 255, lt = bx & 15;
  int l0 = lt << 10;
  __shared__ float s0[1036], s1[1034], s2[1030];
  __shared__ float rs[4];
  int t = threadIdx.x;
  const short* fp = focus0 + ((size_t)((b << 8) | c) << 14);
  if (lt > 0 && lt < 15) {
    const unsigned* fp2 = (const unsigned*)(fp + l0 - 6);
    for (int i2 = t; i2 < 518; i2 += 256) {
      unsigned u = fp2[i2];
      s0[2 * i2] = bf2f((short)(u & 0xFFFF));
      s0[2 * i2 + 1] = bf2f((short)(u >> 16));
    }
  } else {
    for (int i = t; i < 1036; i += 256) {
      int gl = l0 - 6 + i;
      s0[i] = (gl >= 0 && gl < LLEN) ? bf2f(fp[gl]) : 0.f;
    }
  }
  float w0[3], w1[5], w2[7];
  #pragma unroll
  for (int j = 0; j < 3; ++j) w0[j] = f0_w[c * 3 + j];
  #pragma unroll
  for (int j = 0; j < 5; ++j) w1[j] = f1_w[c * 5 + j];
  #pragma unroll
  for (int j = 0; j < 7; ++j) w2[j] = f2_w[c * 7 + j];
  __syncthreads();
  for (int i = t; i < 1034; i += 256) {
    int gl = l0 - 5 + i;
    float z = w0[0] * s0[i] + w0[1] * s0[i + 1] + w0[2] * s0[i + 2];
    s1[i] = (gl >= 0 && gl < LLEN) ? gelu_fast(z) : 0.f;
  }
  __syncthreads();
  for (int i = t; i < 1030; i += 256) {
    int gl = l0 - 3 + i;
    float z = w1[0] * s1[i] + w1[1] * s1[i + 1] + w1[2] * s1[i + 2] +
              w1[3] * s1[i + 3] + w1[4] * s1[i + 4];
    s2[i] = (gl >= 0 && gl < LLEN) ? gelu_fast(z) : 0.f;
  }
  __syncthreads();
  const float* gp = gates + ((size_t)(b << 2) << 14);
  short* op = acc3S + ((size_t)((b << 8) | c) << 15);  // lower 32KiB of mask row
  float lsum = 0.f;
  #pragma unroll
  for (int ii = 0; ii < 2; ++ii) {
    int i = 2 * t + 512 * ii;
    float z0 = w2[0] * s2[i] + w2[1] * s2[i + 1] + w2[2] * s2[i + 2] +
               w2[3] * s2[i + 3] + w2[4] * s2[i + 4] + w2[5] * s2[i + 5] +
               w2[6] * s2[i + 6];
    float z1 = w2[0] * s2[i + 1] + w2[1] * s2[i + 2] + w2[2] * s2[i + 3] +
               w2[3] * s2[i + 4] + w2[4] * s2[i + 5] + w2[5] * s2[i + 6] +
               w2[6] * s2[i + 7];
    float f30 = gelu_fast(z0), f31 = gelu_fast(z1);
    lsum += f30 + f31;
    int l = l0 + i;
    float a0 = s1[i + 5] * gp[l] + s2[i + 3] * gp[LLEN + l] + f30 * gp[2 * LLEN + l];
    float a1 = s1[i + 6] * gp[l + 1] + s2[i + 4] * gp[LLEN + l + 1] +
               f31 * gp[2 * LLEN + l + 1];
    *(unsigned*)&op[l] = bfbits(a0) | (bfbits(a1) << 16);
  }
  float wsv = waveRedSum(lsum);
  if ((t & 63) == 0) rs[t >> 6] = wsv;
  __syncthreads();
  if (t == 0) atomicAdd(&rowsum[(b << 8) | c], rs[0] + rs[1] + rs[2] + rs[3]);
}

// ---------------- K3b: wgf[b][o] = sum_c mix_w[o][c] * gelu(mean_f3[b][c]) ----
__global__ __launch_bounds__(256) void k3b_wgf(
    const float* __restrict__ rowsum, const float* __restrict__ mix_w,
    float* __restrict__ wgf) {
  int b = blockIdx.x;  // 8 blocks
  int t = threadIdx.x;
  __shared__ float gf_s[256];
  gf_s[t] = geluf(rowsum[(b << 8) | t] * (1.0f / 16384.0f));
  __syncthreads();
  const float* wrow = mix_w + t * 256;  // o = t
  float s = 0.f;
  #pragma unroll 8
  for (int c = 0; c < 256; ++c) s += wrow[c] * gf_s[c];
  wgf[(b << 8) | t] = s;
}

// ---------------- K4: m = mix_w@acc3 + wgf*g3 + mix_b -> bf16 (upper half).
//                      128-l tile, 512 thr = 8 waves of PROVEN 64e x 64l. ----
__global__ __launch_bounds__(512) void k4_mix(
    short* maskS, const float* __restrict__ gates, const float* __restrict__ wgf,
    const short* __restrict__ mwb, const float* __restrict__ mix_b) {
  int b = blockIdx.x >> 7, lt = blockIdx.x & 127;
  int l0 = lt << 7;
  __shared__ short xs[128][PAD];
  int t = threadIdx.x;
  {
    // uint2 staging of acc3 bf16: 32 lanes x 8B = 256B contiguous per row.
    int lq = (t & 31) * 4, cg = t >> 5;
    const unsigned short* base =
        (const unsigned short*)maskS + (((size_t)(b << 8)) << 15) + l0 + lq;
    #pragma unroll
    for (int rep = 0; rep < 8; ++rep) {
      int c = rep * 32 + cg * 2;
      uint2 av = *(const uint2*)&base[(size_t)c << 15];
      uint2 bv = *(const uint2*)&base[((size_t)c + 1) << 15];
      *(unsigned*)&xs[lq + 0][c] = (av.x & 0xFFFF) | (bv.x << 16);
      *(unsigned*)&xs[lq + 1][c] = (av.x >> 16) | (bv.x & 0xFFFF0000u);
      *(unsigned*)&xs[lq + 2][c] = (av.y & 0xFFFF) | (bv.y << 16);
      *(unsigned*)&xs[lq + 3][c] = (av.y >> 16) | (bv.y & 0xFFFF0000u);
    }
  }
  __syncthreads();
  int lane = t & 63, wave = t >> 6;
  int we = wave & 3, wl = wave >> 2;
  int r = lane & 15, h = lane >> 4;
  int e0 = we << 6;
  const short (*xsl)[PAD] = (const short (*)[PAD])&xs[wl << 6];
  int lbase = l0 + (wl << 6) + 4 * h;
  f32x4 acc[4][4];
  #pragma unroll
  for (int ef = 0; ef < 4; ++ef)
    #pragma unroll
    for (int lf = 0; lf < 4; ++lf)
      acc[ef][lf] = (f32x4){0.f, 0.f, 0.f, 0.f};
  gemm64(mwb + e0 * 256, xsl, lane, acc);
  float4 g3v[4];
  #pragma unroll
  for (int lf = 0; lf < 4; ++lf)
    g3v[lf] = *(const float4*)&gates[(((size_t)((b << 2) | 3)) << 14) + lbase +
                                     lf * 16];
  #pragma unroll
  for (int ef = 0; ef < 4; ++ef) {
    int o = e0 + ef * 16 + r;
    float base = mix_b[o];
    float wg = wgf[(b << 8) | o];
    short* rowp = maskS + (((size_t)((b << 8) | o) << 15) + 16384) + lbase;
    #pragma unroll
    for (int lf = 0; lf < 4; ++lf) {
      uint2 pk;
      pk.x = bfbits(acc[ef][lf][0] + base + wg * g3v[lf].x) |
             (bfbits(acc[ef][lf][1] + base + wg * g3v[lf].y) << 16);
      pk.y = bfbits(acc[ef][lf][2] + base + wg * g3v[lf].z) |
             (bfbits(acc[ef][lf][3] + base + wg * g3v[lf].w) << 16);
      *(uint2*)(rowp + lf * 16) = pk;
    }
  }
}

// ---------------- K5: softmax over L from bf16 m; out = sigmoid(qz)*mask ----
__global__ __launch_bounds__(512) void k5_softmax(
    const short* __restrict__ maskS, const short* __restrict__ outS,
    float* __restrict__ maskF, float* __restrict__ outF) {
  int row = blockIdx.x;  // b*256 + o
  int t = threadIdx.x;   // 512 threads, 8 waves
  const short* mrow = maskS + ((size_t)row << 15) + 16384;
  const short* qrow = outS + ((size_t)row << 15) + 16384;
  float* mw = maskF + ((size_t)row << 14);
  float* ow = outF + ((size_t)row << 14);
  int lane = t & 63, wave = t >> 6;
  bf16x8 qv[4];
  float f[32];
  float lm = -3.0e38f;
  #pragma unroll
  for (int i = 0; i < 4; ++i) {
    bf16x8 mv = *(const bf16x8*)&mrow[i * 4096 + t * 8];
    qv[i] = *(const bf16x8*)&qrow[i * 4096 + t * 8];
    #pragma unroll
    for (int j = 0; j < 8; ++j) {
      float vf = bf2f(mv[j]);
      f[i * 8 + j] = vf;
      lm = fmaxf(lm, vf);
    }
  }
  __shared__ float redm[8], reds[8];
  {
    #pragma unroll
    for (int o = 32; o > 0; o >>= 1) lm = fmaxf(lm, __shfl_xor(lm, o, 64));
  }
  if (lane == 0) redm[wave] = lm;
  __syncthreads();  // also drains all global loads before writes below
  float M = redm[0];
  #pragma unroll
  for (int w = 1; w < 8; ++w) M = fmaxf(M, redm[w]);
  float ls = 0.f;
  #pragma unroll
  for (int k = 0; k < 32; ++k) {
    f[k] = __expf(f[k] - M);
    ls += f[k];
  }
  float wsum = waveRedSum(ls);
  if (lane == 0) reds[wave] = wsum;
  __syncthreads();
  float S = reds[0];
  #pragma unroll
  for (int w = 1; w < 8; ++w) S += reds[w];
  float inv = fastrcp(S) * (2.0f - S * fastrcp(S));  // one NR step: rel err ~1e-14
  #pragma unroll
  for (int i = 0; i < 4; ++i) {
    float mk[8], oo[8];
    #pragma unroll
    for (int j = 0; j < 8; ++j) {
      mk[j] = f[i * 8 + j] * inv;
      float sig = fastrcp(1.0f + __expf(-bf2f(qv[i][j])));
      oo[j] = sig * mk[j];
    }
    float* mp = &mw[i * 4096 + t * 8];
    float* op = &ow[i * 4096 + t * 8];
    *(float4*)mp = (float4){mk[0], mk[1], mk[2], mk[3]};
    *(float4*)(mp + 4) = (float4){mk[4], mk[5], mk[6], mk[7]};
    *(float4*)op = (float4){oo[0], oo[1], oo[2], oo[3]};
    *(float4*)(op + 4) = (float4){oo[4], oo[5], oo[6], oo[7]};
  }
}

extern "C" void kernel_launch(void* const* d_in, const int* in_sizes, int n_in,
                              void* d_out, int out_size, void* d_ws, size_t ws_size,
                              hipStream_t stream) {
  const float* x     = (const float*)d_in[0];
  const float* q_w   = (const float*)d_in[1];
  const float* q_b   = (const float*)d_in[2];
  const float* v_w   = (const float*)d_in[3];
  const float* v_b   = (const float*)d_in[4];
  const float* g_w   = (const float*)d_in[5];
  const float* g_b   = (const float*)d_in[6];
  const float* f0_w  = (const float*)d_in[7];
  const float* f1_w  = (const float*)d_in[8];
  const float* f2_w  = (const float*)d_in[9];
  const float* mix_w = (const float*)d_in[10];
  const float* mix_b = (const float*)d_in[11];

  float* outbuf  = (float*)d_out;                       // out [8,256,16384] f32
  float* maskbuf = outbuf + (size_t)8 * 256 * 16384;    // mask [8,256,16384] f32
  short* outS  = (short*)outbuf;   // per-row: [32KiB out f32][32KiB qz bf16]
  short* maskS = (short*)maskbuf;  // per-row: [32KiB acc3 bf16][32KiB m bf16]

  char* ws = (char*)d_ws;
  short* vwb    = (short*)(ws + 0);        // 131072 B
  short* qwb    = (short*)(ws + 131072);   // 131072 B
  short* mwb    = (short*)(ws + 262144);   // 131072 B
  short* gwb    = (short*)(ws + 393216);   // 8192 B (16x256 bf16, rows>=4 zero)
  float* rowsum = (float*)(ws + 401408);   // 8192 B
  float* wgf    = (float*)(ws + 409600);   // 8192 B
  float* gates  = (float*)(ws + 417792);   // 2097152 B
  short* focus0 = (short*)(ws + 2514944);  // 67108864 B

  k0_convert<<<dim3(256), dim3(256), 0, stream>>>(q_w, v_w, g_w, mix_w,
                                                  qwb, vwb, gwb, mwb, rowsum);
  k1_qvg<<<dim3(1024), dim3(512), 0, stream>>>(x, vwb, qwb, gwb, v_b, q_b, g_b,
                                               focus0, outS, gates);
  k2_conv<<<dim3(32768), dim3(256), 0, stream>>>(focus0, gates, f0_w, f1_w, f2_w,
                                                 maskS, rowsum);
  k3b_wgf<<<dim3(8), dim3(256), 0, stream>>>(rowsum, mix_w, wgf);
  k4_mix<<<dim3(1024), dim3(512), 0, stream>>>(maskS, gates, wgf, mwb, mix_b);
  k5_softmax<<<dim3(2048), dim3(512), 0, stream>>>(maskS, outS, maskbuf, outbuf);
}

// Round 10
// 367.748 us; speedup vs baseline: 1.1350x; 1.0277x over previous
//
#include <hip/hip_runtime.h>

#define LLEN 16384
#define PAD 258  // 516B row stride; 129 dwords == 1 mod 32 -> 2-way (free) LDS aliasing

typedef short bf16x8 __attribute__((ext_vector_type(8)));
typedef float f32x4 __attribute__((ext_vector_type(4)));

__device__ __forceinline__ unsigned bfbits(float f) {
  union { float f; unsigned u; } v; v.f = f;
  return (v.u + 0x7FFFu + ((v.u >> 16) & 1u)) >> 16;
}
__device__ __forceinline__ short f2bf(float f) { return (short)bfbits(f); }
__device__ __forceinline__ float bf2f(short s) {
  union { unsigned u; float f; } v;
  v.u = ((unsigned)(unsigned short)s) << 16;
  return v.f;
}
// v_rcp_f32: 1 op vs ~10 for IEEE divide; rel err ~1.2e-7 (outputs ~6e-5 ->
// induced abs err ~1e-11 << 4.8e-7 measured absmax)
__device__ __forceinline__ float fastrcp(float x) {
  float r;
  asm("v_rcp_f32 %0, %1" : "=v"(r) : "v"(x));
  return r;
}
__device__ __forceinline__ float geluf(float x) {  // exact (gf path only)
  return 0.5f * x * (1.0f + erff(x * 0.70710678118654752f));
}
// Fast GELU for conv chain (verified R4-R9: absmax unchanged at 4.77e-7)
__device__ __forceinline__ float gelu_fast(float x) {
  return x * fastrcp(1.0f + __expf(-1.702f * x));
}
__device__ __forceinline__ float waveRedSum(float v) {
  #pragma unroll
  for (int o = 32; o > 0; o >>= 1) v += __shfl_xor(v, o, 64);
  return v;
}

// ---------------- K0: weights -> bf16, zero rowsum ----------------
__global__ __launch_bounds__(256) void k0_convert(
    const float* __restrict__ qw, const float* __restrict__ vw,
    const float* __restrict__ gw, const float* __restrict__ mw,
    short* __restrict__ qwb, short* __restrict__ vwb,
    short* __restrict__ gwb, short* __restrict__ mwb,
    float* __restrict__ rowsum) {
  int idx = blockIdx.x * 256 + threadIdx.x;  // 65536 threads
  qwb[idx] = f2bf(qw[idx]);
  vwb[idx] = f2bf(vw[idx]);
  mwb[idx] = f2bf(mw[idx]);
  if (idx < 4096) {
    int r = idx >> 8, c = idx & 255;
    gwb[idx] = (r < 4) ? f2bf(gw[r * 256 + c]) : (short)0;
  }
  if (idx < 2048) rowsum[idx] = 0.f;
}

// 64x64-per-wave GEMM over K=256 from LDS tile xs[l][c] (bf16, stride PAD).
// A = x fragment (M = l), B = weight fragment (N = e).
// acc[ef][lf][i] <-> e = ef*16 + (lane&15), l = lf*16 + 4*(lane>>4) + i
// (PROVEN R3 shape -- unchanged.)
__device__ __forceinline__ void gemm64(const short* __restrict__ wmat,
                                       const short (*xs)[PAD], int lane,
                                       f32x4 acc[4][4]) {
  int r = lane & 15, h = lane >> 4;
  #pragma unroll
  for (int k0 = 0; k0 < 256; k0 += 32) {
    bf16x8 xfr[4];
    #pragma unroll
    for (int lf = 0; lf < 4; ++lf)
      xfr[lf] = *(const bf16x8*)&xs[lf * 16 + r][k0 + 8 * h];
    #pragma unroll
    for (int ef = 0; ef < 4; ++ef) {
      bf16x8 wfr = *(const bf16x8*)(wmat + (ef * 16 + r) * 256 + k0 + 8 * h);
      #pragma unroll
      for (int lf = 0; lf < 4; ++lf)
        acc[ef][lf] = __builtin_amdgcn_mfma_f32_16x16x32_bf16(xfr[lf], wfr,
                                                              acc[ef][lf], 0, 0, 0);
    }
  }
}

// Packed epilogue: 4 consecutive-l f32 + bias -> 2 dwords of bf16 (8B store)
__device__ __forceinline__ void store_bf4(short* p, f32x4 a, float bias) {
  uint2 pk;
  pk.x = bfbits(a[0] + bias) | (bfbits(a[1] + bias) << 16);
  pk.y = bfbits(a[2] + bias) | (bfbits(a[3] + bias) << 16);
  *(uint2*)p = pk;
}

// ---------------- K1: focus0 = v_w@x+v_b (bf16), qz = q_w@x+q_b (bf16),
//     gates = g_w@x+g_b.  128-l tile, 512 thr = 8 waves of PROVEN 64e x 64l.
//     Staging: ALL 16 float4 loads issued into registers before any convert
//     (256B/thread in flight) -- latency-starvation fix. lb(512,4) = LDS-
//     matched residency, VGPR cap 128. ----
__global__ __launch_bounds__(512, 4) void k1_qvg(
    const float* __restrict__ x, const short* __restrict__ vwb,
    const short* __restrict__ qwb, const short* __restrict__ gwb,
    const float* __restrict__ v_b, const float* __restrict__ q_b,
    const float* __restrict__ g_b, short* __restrict__ focus0,
    short* __restrict__ qzS, float* __restrict__ gates) {
  int b = blockIdx.x >> 7, lt = blockIdx.x & 127;
  int l0 = lt << 7;  // 128 l per tile
  __shared__ short xs[128][PAD];
  int t = threadIdx.x;
  {
    // float4 staging: 32 lanes x 16B = 512B contiguous per channel row.
    int lq = (t & 31) * 4, cg = t >> 5;  // 16 c-groups
    const float* xb = x + ((size_t)b << 22) + l0 + lq;
    float4 va[8], vb[8];
    #pragma unroll
    for (int rep = 0; rep < 8; ++rep) {
      int c = rep * 32 + cg * 2;
      va[rep] = *(const float4*)&xb[(size_t)c << 14];
      vb[rep] = *(const float4*)&xb[((size_t)c + 1) << 14];
    }
    #pragma unroll
    for (int rep = 0; rep < 8; ++rep) {
      int c = rep * 32 + cg * 2;
      *(unsigned*)&xs[lq + 0][c] = bfbits(va[rep].x) | (bfbits(vb[rep].x) << 16);
      *(unsigned*)&xs[lq + 1][c] = bfbits(va[rep].y) | (bfbits(vb[rep].y) << 16);
      *(unsigned*)&xs[lq + 2][c] = bfbits(va[rep].z) | (bfbits(vb[rep].z) << 16);
      *(unsigned*)&xs[lq + 3][c] = bfbits(va[rep].w) | (bfbits(vb[rep].w) << 16);
    }
  }
  __syncthreads();
  int lane = t & 63, wave = t >> 6;
  int we = wave & 3, wl = wave >> 2;  // 4 e-ranges x 2 l-subtiles
  int r = lane & 15, h = lane >> 4;
  int e0 = we << 6;
  const short (*xsl)[PAD] = (const short (*)[PAD])&xs[wl << 6];
  int lbase = l0 + (wl << 6) + 4 * h;
  f32x4 acc[4][4];

  // ---- V GEMM -> focus0 (bf16)
  #pragma unroll
  for (int ef = 0; ef < 4; ++ef)
    #pragma unroll
    for (int lf = 0; lf < 4; ++lf)
      acc[ef][lf] = (f32x4){0.f, 0.f, 0.f, 0.f};
  gemm64(vwb + e0 * 256, xsl, lane, acc);
  #pragma unroll
  for (int ef = 0; ef < 4; ++ef) {
    int e = e0 + ef * 16 + r;
    float bias = v_b[e];
    short* rowp = focus0 + ((size_t)((b << 8) | e) << 14) + lbase;
    #pragma unroll
    for (int lf = 0; lf < 4; ++lf)
      store_bf4(rowp + lf * 16, acc[ef][lf], bias);
  }

  // ---- Q GEMM -> qz (bf16, upper 32KiB of out-region rows; sigmoid in K5)
  #pragma unroll
  for (int ef = 0; ef < 4; ++ef)
    #pragma unroll
    for (int lf = 0; lf < 4; ++lf)
      acc[ef][lf] = (f32x4){0.f, 0.f, 0.f, 0.f};
  gemm64(qwb + e0 * 256, xsl, lane, acc);
  #pragma unroll
  for (int ef = 0; ef < 4; ++ef) {
    int e = e0 + ef * 16 + r;
    float bias = q_b[e];
    short* rowp = qzS + (((size_t)((b << 8) | e) << 15) + 16384) + lbase;
    #pragma unroll
    for (int lf = 0; lf < 4; ++lf)
      store_bf4(rowp + lf * 16, acc[ef][lf], bias);
  }

  // ---- gates: waves with we==0 (wl = 0,1 cover the two 64-l subtiles)
  if (we == 0) {
    f32x4 gacc[4];
    #pragma unroll
    for (int lf = 0; lf < 4; ++lf) gacc[lf] = (f32x4){0.f, 0.f, 0.f, 0.f};
    #pragma unroll
    for (int k0 = 0; k0 < 256; k0 += 32) {
      bf16x8 wfr = *(const bf16x8*)(gwb + r * 256 + k0 + 8 * h);
      #pragma unroll
      for (int lf = 0; lf < 4; ++lf) {
        bf16x8 xfr = *(const bf16x8*)&xsl[lf * 16 + r][k0 + 8 * h];
        gacc[lf] = __builtin_amdgcn_mfma_f32_16x16x32_bf16(xfr, wfr, gacc[lf], 0, 0, 0);
      }
    }
    if (r < 4) {  // col = gate row g = r
      float gb = g_b[r];
      float* gp = gates + (((size_t)((b << 2) | r)) << 14) + lbase;
      #pragma unroll
      for (int lf = 0; lf < 4; ++lf) {
        float4 o = {gacc[lf][0] + gb, gacc[lf][1] + gb,
                    gacc[lf][2] + gb, gacc[lf][3] + gb};
        *(float4*)(gp + lf * 16) = o;
      }
    }
  }
}

// ---------------- K2: fused 3-level depthwise conv + gelu chain,
//                      acc3 (bf16) -> lower half of mask rows; rowsum atomics ----
__global__ __launch_bounds__(256) void k2_conv(
    const short* __restrict__ focus0, const float* __restrict__ gates,
    const float* __restrict__ f0_w, const float* __restrict__ f1_w,
    const float* __restrict__ f2_w, short* __restrict__ acc3S,
    float* __restrict__ rowsum) {
  int bx = blockIdx.x;
  int b = bx >> 12, c = (bx >> 4) & 255, lt = bx & 15;
  int l0 = lt << 10;
  __shared__ float s0[1036], s1[1034], s2[1030];
  __shared__ float rs[4];
  int t = threadIdx.x;
  const short* fp = focus0 + ((size_t)((b << 8) | c) << 14);
  if (lt > 0 && lt < 15) {
    const unsigned* fp2 = (const unsigned*)(fp + l0 - 6);
    for (int i2 = t; i2 < 518; i2 += 256) {
      unsigned u = fp2[i2];
      s0[2 * i2] = bf2f((short)(u & 0xFFFF));
      s0[2 * i2 + 1] = bf2f((short)(u >> 16));
    }
  } else {
    for (int i = t; i < 1036; i += 256) {
      int gl = l0 - 6 + i;
      s0[i] = (gl >= 0 && gl < LLEN) ? bf2f(fp[gl]) : 0.f;
    }
  }
  float w0[3], w1[5], w2[7];
  #pragma unroll
  for (int j = 0; j < 3; ++j) w0[j] = f0_w[c * 3 + j];
  #pragma unroll
  for (int j = 0; j < 5; ++j) w1[j] = f1_w[c * 5 + j];
  #pragma unroll
  for (int j = 0; j < 7; ++j) w2[j] = f2_w[c * 7 + j];
  __syncthreads();
  for (int i = t; i < 1034; i += 256) {
    int gl = l0 - 5 + i;
    float z = w0[0] * s0[i] + w0[1] * s0[i + 1] + w0[2] * s0[i + 2];
    s1[i] = (gl >= 0 && gl < LLEN) ? gelu_fast(z) : 0.f;
  }
  __syncthreads();
  for (int i = t; i < 1030; i += 256) {
    int gl = l0 - 3 + i;
    float z = w1[0] * s1[i] + w1[1] * s1[i + 1] + w1[2] * s1[i + 2] +
              w1[3] * s1[i + 3] + w1[4] * s1[i + 4];
    s2[i] = (gl >= 0 && gl < LLEN) ? gelu_fast(z) : 0.f;
  }
  __syncthreads();
  const float* gp = gates + ((size_t)(b << 2) << 14);
  short* op = acc3S + ((size_t)((b << 8) | c) << 15);  // lower 32KiB of mask row
  float lsum = 0.f;
  #pragma unroll
  for (int ii = 0; ii < 2; ++ii) {
    int i = 2 * t + 512 * ii;
    float z0 = w2[0] * s2[i] + w2[1] * s2[i + 1] + w2[2] * s2[i + 2] +
               w2[3] * s2[i + 3] + w2[4] * s2[i + 4] + w2[5] * s2[i + 5] +
               w2[6] * s2[i + 6];
    float z1 = w2[0] * s2[i + 1] + w2[1] * s2[i + 2] + w2[2] * s2[i + 3] +
               w2[3] * s2[i + 4] + w2[4] * s2[i + 5] + w2[5] * s2[i + 6] +
               w2[6] * s2[i + 7];
    float f30 = gelu_fast(z0), f31 = gelu_fast(z1);
    lsum += f30 + f31;
    int l = l0 + i;
    float a0 = s1[i + 5] * gp[l] + s2[i + 3] * gp[LLEN + l] + f30 * gp[2 * LLEN + l];
    float a1 = s1[i + 6] * gp[l + 1] + s2[i + 4] * gp[LLEN + l + 1] +
               f31 * gp[2 * LLEN + l + 1];
    *(unsigned*)&op[l] = bfbits(a0) | (bfbits(a1) << 16);
  }
  float wsv = waveRedSum(lsum);
  if ((t & 63) == 0) rs[t >> 6] = wsv;
  __syncthreads();
  if (t == 0) atomicAdd(&rowsum[(b << 8) | c], rs[0] + rs[1] + rs[2] + rs[3]);
}

// ---------------- K3b: wgf[b][o] = sum_c mix_w[o][c] * gelu(mean_f3[b][c]) ----
__global__ __launch_bounds__(256) void k3b_wgf(
    const float* __restrict__ rowsum, const float* __restrict__ mix_w,
    float* __restrict__ wgf) {
  int b = blockIdx.x;  // 8 blocks
  int t = threadIdx.x;
  __shared__ float gf_s[256];
  gf_s[t] = geluf(rowsum[(b << 8) | t] * (1.0f / 16384.0f));
  __syncthreads();
  const float* wrow = mix_w + t * 256;  // o = t
  float s = 0.f;
  #pragma unroll 8
  for (int c = 0; c < 256; ++c) s += wrow[c] * gf_s[c];
  wgf[(b << 8) | t] = s;
}

// ---------------- K4: m = mix_w@acc3 + wgf*g3 + mix_b -> bf16 (upper half).
//                      128-l tile, 512 thr; prefetch-all staging like K1. ----
__global__ __launch_bounds__(512, 4) void k4_mix(
    short* maskS, const float* __restrict__ gates, const float* __restrict__ wgf,
    const short* __restrict__ mwb, const float* __restrict__ mix_b) {
  int b = blockIdx.x >> 7, lt = blockIdx.x & 127;
  int l0 = lt << 7;
  __shared__ short xs[128][PAD];
  int t = threadIdx.x;
  {
    // uint2 staging of acc3 bf16: 32 lanes x 8B = 256B contiguous per row.
    // ALL 16 loads issued before first use (128B/thread in flight).
    int lq = (t & 31) * 4, cg = t >> 5;
    const unsigned short* base =
        (const unsigned short*)maskS + (((size_t)(b << 8)) << 15) + l0 + lq;
    uint2 av[8], bv[8];
    #pragma unroll
    for (int rep = 0; rep < 8; ++rep) {
      int c = rep * 32 + cg * 2;
      av[rep] = *(const uint2*)&base[(size_t)c << 15];
      bv[rep] = *(const uint2*)&base[((size_t)c + 1) << 15];
    }
    #pragma unroll
    for (int rep = 0; rep < 8; ++rep) {
      int c = rep * 32 + cg * 2;
      *(unsigned*)&xs[lq + 0][c] = (av[rep].x & 0xFFFF) | (bv[rep].x << 16);
      *(unsigned*)&xs[lq + 1][c] = (av[rep].x >> 16) | (bv[rep].x & 0xFFFF0000u);
      *(unsigned*)&xs[lq + 2][c] = (av[rep].y & 0xFFFF) | (bv[rep].y << 16);
      *(unsigned*)&xs[lq + 3][c] = (av[rep].y >> 16) | (bv[rep].y & 0xFFFF0000u);
    }
  }
  __syncthreads();
  int lane = t & 63, wave = t >> 6;
  int we = wave & 3, wl = wave >> 2;
  int r = lane & 15, h = lane >> 4;
  int e0 = we << 6;
  const short (*xsl)[PAD] = (const short (*)[PAD])&xs[wl << 6];
  int lbase = l0 + (wl << 6) + 4 * h;
  f32x4 acc[4][4];
  #pragma unroll
  for (int ef = 0; ef < 4; ++ef)
    #pragma unroll
    for (int lf = 0; lf < 4; ++lf)
      acc[ef][lf] = (f32x4){0.f, 0.f, 0.f, 0.f};
  gemm64(mwb + e0 * 256, xsl, lane, acc);
  float4 g3v[4];
  #pragma unroll
  for (int lf = 0; lf < 4; ++lf)
    g3v[lf] = *(const float4*)&gates[(((size_t)((b << 2) | 3)) << 14) + lbase +
                                     lf * 16];
  #pragma unroll
  for (int ef = 0; ef < 4; ++ef) {
    int o = e0 + ef * 16 + r;
    float base = mix_b[o];
    float wg = wgf[(b << 8) | o];
    short* rowp = maskS + (((size_t)((b << 8) | o) << 15) + 16384) + lbase;
    #pragma unroll
    for (int lf = 0; lf < 4; ++lf) {
      uint2 pk;
      pk.x = bfbits(acc[ef][lf][0] + base + wg * g3v[lf].x) |
             (bfbits(acc[ef][lf][1] + base + wg * g3v[lf].y) << 16);
      pk.y = bfbits(acc[ef][lf][2] + base + wg * g3v[lf].z) |
             (bfbits(acc[ef][lf][3] + base + wg * g3v[lf].w) << 16);
      *(uint2*)(rowp + lf * 16) = pk;
    }
  }
}

// ---------------- K5: softmax over L from bf16 m; out = sigmoid(qz)*mask ----
__global__ __launch_bounds__(512) void k5_softmax(
    const short* __restrict__ maskS, const short* __restrict__ outS,
    float* __restrict__ maskF, float* __restrict__ outF) {
  int row = blockIdx.x;  // b*256 + o
  int t = threadIdx.x;   // 512 threads, 8 waves
  const short* mrow = maskS + ((size_t)row << 15) + 16384;
  const short* qrow = outS + ((size_t)row << 15) + 16384;
  float* mw = maskF + ((size_t)row << 14);
  float* ow = outF + ((size_t)row << 14);
  int lane = t & 63, wave = t >> 6;
  bf16x8 qv[4];
  float f[32];
  float lm = -3.0e38f;
  #pragma unroll
  for (int i = 0; i < 4; ++i) {
    bf16x8 mv = *(const bf16x8*)&mrow[i * 4096 + t * 8];
    qv[i] = *(const bf16x8*)&qrow[i * 4096 + t * 8];
    #pragma unroll
    for (int j = 0; j < 8; ++j) {
      float vf = bf2f(mv[j]);
      f[i * 8 + j] = vf;
      lm = fmaxf(lm, vf);
    }
  }
  __shared__ float redm[8], reds[8];
  {
    #pragma unroll
    for (int o = 32; o > 0; o >>= 1) lm = fmaxf(lm, __shfl_xor(lm, o, 64));
  }
  if (lane == 0) redm[wave] = lm;
  __syncthreads();  // also drains all global loads before writes below
  float M = redm[0];
  #pragma unroll
  for (int w = 1; w < 8; ++w) M = fmaxf(M, redm[w]);
  float ls = 0.f;
  #pragma unroll
  for (int k = 0; k < 32; ++k) {
    f[k] = __expf(f[k] - M);
    ls += f[k];
  }
  float wsum = waveRedSum(ls);
  if (lane == 0) reds[wave] = wsum;
  __syncthreads();
  float S = reds[0];
  #pragma unroll
  for (int w = 1; w < 8; ++w) S += reds[w];
  float inv = fastrcp(S) * (2.0f - S * fastrcp(S));  // one NR step: rel err ~1e-14
  #pragma unroll
  for (int i = 0; i < 4; ++i) {
    float mk[8], oo[8];
    #pragma unroll
    for (int j = 0; j < 8; ++j) {
      mk[j] = f[i * 8 + j] * inv;
      float sig = fastrcp(1.0f + __expf(-bf2f(qv[i][j])));
      oo[j] = sig * mk[j];
    }
    float* mp = &mw[i * 4096 + t * 8];
    float* op = &ow[i * 4096 + t * 8];
    *(float4*)mp = (float4){mk[0], mk[1], mk[2], mk[3]};
    *(float4*)(mp + 4) = (float4){mk[4], mk[5], mk[6], mk[7]};
    *(float4*)op = (float4){oo[0], oo[1], oo[2], oo[3]};
    *(float4*)(op + 4) = (float4){oo[4], oo[5], oo[6], oo[7]};
  }
}

extern "C" void kernel_launch(void* const* d_in, const int* in_sizes, int n_in,
                              void* d_out, int out_size, void* d_ws, size_t ws_size,
                              hipStream_t stream) {
  const float* x     = (const float*)d_in[0];
  const float* q_w   = (const float*)d_in[1];
  const float* q_b   = (const float*)d_in[2];
  const float* v_w   = (const float*)d_in[3];
  const float* v_b   = (const float*)d_in[4];
  const float* g_w   = (const float*)d_in[5];
  const float* g_b   = (const float*)d_in[6];
  const float* f0_w  = (const float*)d_in[7];
  const float* f1_w  = (const float*)d_in[8];
  const float* f2_w  = (const float*)d_in[9];
  const float* mix_w = (const float*)d_in[10];
  const float* mix_b = (const float*)d_in[11];

  float* outbuf  = (float*)d_out;                       // out [8,256,16384] f32
  float* maskbuf = outbuf + (size_t)8 * 256 * 16384;    // mask [8,256,16384] f32
  short* outS  = (short*)outbuf;   // per-row: [32KiB out f32][32KiB qz bf16]
  short* maskS = (short*)maskbuf;  // per-row: [32KiB acc3 bf16][32KiB m bf16]

  char* ws = (char*)d_ws;
  short* vwb    = (short*)(ws + 0);        // 131072 B
  short* qwb    = (short*)(ws + 131072);   // 131072 B
  short* mwb    = (short*)(ws + 262144);   // 131072 B
  short* gwb    = (short*)(ws + 393216);   // 8192 B (16x256 bf16, rows>=4 zero)
  float* rowsum = (float*)(ws + 401408);   // 8192 B
  float* wgf    = (float*)(ws + 409600);   // 8192 B
  float* gates  = (float*)(ws + 417792);   // 2097152 B
  short* focus0 = (short*)(ws + 2514944);  // 67108864 B

  k0_convert<<<dim3(256), dim3(256), 0, stream>>>(q_w, v_w, g_w, mix_w,
                                                  qwb, vwb, gwb, mwb, rowsum);
  k1_qvg<<<dim3(1024), dim3(512), 0, stream>>>(x, vwb, qwb, gwb, v_b, q_b, g_b,
                                               focus0, outS, gates);
  k2_conv<<<dim3(32768), dim3(256), 0, stream>>>(focus0, gates, f0_w, f1_w, f2_w,
                                                 maskS, rowsum);
  k3b_wgf<<<dim3(8), dim3(256), 0, stream>>>(rowsum, mix_w, wgf);
  k4_mix<<<dim3(1024), dim3(512), 0, stream>>>(maskS, gates, wgf, mwb, mix_b);
  k5_softmax<<<dim3(2048), dim3(512), 0, stream>>>(maskS, outS, maskbuf, outbuf);
}